// Round 11
// baseline (230.923 us; speedup 1.0000x reference)
//
#include <hip/hip_runtime.h>

typedef _Float16 h8 __attribute__((ext_vector_type(8)));
typedef _Float16 h4 __attribute__((ext_vector_type(4)));
typedef float f4 __attribute__((ext_vector_type(4)));

typedef __attribute__((address_space(1))) const void GV;
typedef __attribute__((address_space(3))) void SV;

__device__ __forceinline__ void async16(const void* g, void* s) {
  __builtin_amdgcn_global_load_lds((GV*)g, (SV*)s, 16, 0, 0);
}

// x: (4,4096,1024) fp32; w_qkv: (3072,1024) fp32 rows e=h*192+d*3+t;
// mem_kv: (2,16,4,64) fp32; mask: (4,4096) int32; out: (4,4096,1024) fp32.
//
// COMPACTED PIPELINE: compact (scan) packs unmasked row ids to the front
// of idx[b]. cvt converts only live slots (swizzle keyed by slot), zero-
// fills tail to 128 boundary, plus W permute+swizzle and masked-out-row
// zeroing. GEMMs read xh linearly; blocks past cnt[b] exit.
// kv_gemm (256,4): 128-reg cap = exact 64 VGPR + 64 AGPR fit, 4 blk/CU.
// qpv n-tile 64 (one head/block): 1056 live blocks, 24KB LDS, 5 blk/CU
// -> per-CU quantization waste <10% (was ~30% at 528 blocks / 3 cap).
// xh/wh BANK-SWIZZLED: chunk ch ^= (slot&7) within each 128-B window.
// wh rows PERMUTED: [0,2048) = [h][k:64|v:64], [2048,3072) = [h][q:64].

#define XC 2097152   // xh h8-chunk positions (16777216/8)
#define WC 393216    // w h8-chunks (3145728/8)
#define ZC 4194304   // out float4 count (zero pass)

// ---------------- kernel 0: per-batch mask compaction (scan) -------------
__global__ __launch_bounds__(1024) void compact(const int4* __restrict__ mask4,
                                                int* __restrict__ cnt,
                                                int* __restrict__ idx) {
  const int b = blockIdx.x;
  const int t = threadIdx.x;            // 0..1023
  const int lane = t & 63, w = t >> 6;  // 16 waves

  const int4 m4 = mask4[b * 1024 + t];
  int m[4] = {m4.x, m4.y, m4.z, m4.w};
  const int c = (m[0] != 0) + (m[1] != 0) + (m[2] != 0) + (m[3] != 0);

  int inc = c;
#pragma unroll
  for (int off = 1; off < 64; off <<= 1) {
    const int v = __shfl_up(inc, off);
    if (lane >= off) inc += v;
  }
  __shared__ int wtot[16];
  if (lane == 63) wtot[w] = inc;
  __syncthreads();
  int prev = 0;
#pragma unroll
  for (int i = 0; i < 16; ++i)
    if (i < w) prev += wtot[i];
  const int excl = prev + inc - c;

  if (t == 1023) cnt[b] = excl + c;

  int* const ib = idx + b * 4096;
  int p = excl;
  int q = t * 4 - excl;
#pragma unroll
  for (int r = 0; r < 4; ++r) {
    const int row = t * 4 + r;
    if (m[r]) ib[p++] = row;
    else      ib[4095 - q++] = row;
  }
}

// ---------------- kernel 1: cvt (live slots only) + W + out-zero ---------
__global__ __launch_bounds__(256) void cvt_f16(const float4* __restrict__ x,
                                               const float4* __restrict__ w,
                                               const int* __restrict__ mask,
                                               const int* __restrict__ cnt,
                                               const int* __restrict__ idx,
                                               h8* __restrict__ xh,
                                               h8* __restrict__ wh,
                                               float4* __restrict__ out) {
  int t = blockIdx.x * 256 + threadIdx.x;
  if (t < XC) {
    const int slot = t >> 7, cd = t & 127;   // dest chunk
    const int b = slot >> 12, s = slot & 4095;
    const int cb = cnt[b];
    const int lim = (cb + 127) & ~127;
    if (s < lim) {
      h8 o;
      if (s < cb) {
        const int ri = idx[b * 4096 + s];
        const int cs = (cd & 120) | ((cd & 7) ^ (s & 7));  // src chunk
        const size_t rb = (size_t)(b * 4096 + ri) * 256;
        float4 a = x[rb + cs * 2], bb = x[rb + cs * 2 + 1];
        o = h8{(_Float16)a.x,  (_Float16)a.y,  (_Float16)a.z,  (_Float16)a.w,
               (_Float16)bb.x, (_Float16)bb.y, (_Float16)bb.z, (_Float16)bb.w};
      } else {
        o = h8{(_Float16)0.f, (_Float16)0.f, (_Float16)0.f, (_Float16)0.f,
               (_Float16)0.f, (_Float16)0.f, (_Float16)0.f, (_Float16)0.f};
      }
      xh[(size_t)slot * 128 + cd] = o;
    }
  } else if (t < XC + WC) {
    const int u = t - XC;  // 0..393215
    const int rp = u >> 7, c7 = u & 127;
    int sr;
    if (rp < 2048) {
      int h = rp >> 7, c = rp & 127;
      sr = h * 192 + ((c < 64) ? (c * 3 + 1) : ((c - 64) * 3 + 2));
    } else {
      int q = rp - 2048;
      sr = (q >> 6) * 192 + (q & 63) * 3;
    }
    const int dst = (rp << 7) | (c7 & 120) | ((c7 & 7) ^ (rp & 7));
    float4 a = w[sr * 256 + c7 * 2], b = w[sr * 256 + c7 * 2 + 1];
    h8 o = {(_Float16)a.x, (_Float16)a.y, (_Float16)a.z, (_Float16)a.w,
            (_Float16)b.x, (_Float16)b.y, (_Float16)b.z, (_Float16)b.w};
    wh[dst] = o;
  } else {
    const int u = t - (XC + WC);   // 0..ZC-1
    const int row = u >> 8, c = u & 255;
    if (!mask[row]) {
      const float4 z4 = {0.f, 0.f, 0.f, 0.f};
      out[(size_t)row * 256 + c] = z4;
    }
  }
}

// ---------------- kernel 2: kv GEMM + ctx-partial epilogue (128^2) -------
// grid (16 n-tiles, 128 m-tiles), 256 thr = 4 waves (2x2), BK=64.
// (256,4): 128-reg cap = exact 64 VGPR + 64 AGPR fit, 4 blocks/CU.
__global__ __launch_bounds__(256, 4) void kv_gemm(const _Float16* __restrict__ A,
                                                  const _Float16* __restrict__ W,
                                                  const int* __restrict__ cnt,
                                                  float* __restrict__ part) {
  const int my = blockIdx.y;
  const int b = my >> 5, lc = my & 31;
  const int cb = cnt[b];
  if (lc * 128 >= cb) return;

  __shared__ _Float16 smem[128 * 128];  // 32 KB: As 16K + Bs 16K; epi reuse
  _Float16* const As = smem;
  _Float16* const Bs = smem + 8192;
  const int tid = threadIdx.x;
  const int lane = tid & 63, wid = tid >> 6;
  const int wm = wid & 1, wn = wid >> 1;
  const int l15 = lane & 15, quad = lane >> 4;
  const int n0 = blockIdx.x * 128;
  const int m0 = b * 4096 + lc * 128;  // compacted slot base

  const f4 z = {0.f, 0.f, 0.f, 0.f};
  f4 acc[4][4];
#pragma unroll
  for (int i = 0; i < 4; ++i)
#pragma unroll
    for (int j = 0; j < 4; ++j) acc[i][j] = z;

  const int swz = l15 & 7;

  for (int kt = 0; kt < 16; ++kt) {
    const int k0 = kt * 64;
#pragma unroll
    for (int it = 0; it < 4; ++it) {
      const int idxl = it * 256 + tid;
      const int row = idxl >> 3, cg = idxl & 7;
      async16(A + ((size_t)(m0 + row) * 1024 + k0 + cg * 8), As + idxl * 8);
      async16(W + ((size_t)(n0 + row) * 1024 + k0 + cg * 8), Bs + idxl * 8);
    }
    __syncthreads();
#pragma unroll
    for (int ks = 0; ks < 2; ++ks) {
      const int pc = ((ks << 2) | quad) ^ swz;
      h8 af[4], bf[4];
#pragma unroll
      for (int i = 0; i < 4; ++i)
        af[i] = *(const h8*)&As[(wm * 64 + i * 16 + l15) * 64 + pc * 8];
#pragma unroll
      for (int j = 0; j < 4; ++j)
        bf[j] = *(const h8*)&Bs[(wn * 64 + j * 16 + l15) * 64 + pc * 8];
#pragma unroll
      for (int i = 0; i < 4; ++i)
#pragma unroll
        for (int j = 0; j < 4; ++j)
          acc[i][j] = __builtin_amdgcn_mfma_f32_16x16x32_f16(af[i], bf[j], acc[i][j], 0, 0, 0);
    }
    __syncthreads();
  }

  // ---- kv epilogue: exp(k) for valid slots, LDS round-trip, ctx partial --
  const int h = n0 >> 7;
  const int bh = b * 16 + h;
  const int jbase = lc * 128;
#pragma unroll
  for (int i = 0; i < 4; ++i) {
    const int nb = wm * 64 + i * 16 + quad * 4;
#pragma unroll
    for (int j = 0; j < 4; ++j) {
      const int c = wn * 64 + j * 16 + l15;
      h4 o;
      if (wn == 0) {
#pragma unroll
        for (int r = 0; r < 4; ++r)
          o[r] = (_Float16)((jbase + nb + r < cb) ? __expf(acc[i][j][r]) : 0.f);
      } else {
#pragma unroll
        for (int r = 0; r < 4; ++r) o[r] = (_Float16)acc[i][j][r];
      }
      *(h4*)&smem[c * 128 + (nb ^ (l15 * 8))] = o;
    }
  }
  __syncthreads();
  f4 cacc[5];
#pragma unroll
  for (int i = 0; i < 5; ++i) cacc[i] = z;
  h8 bones;
  {
    const _Float16 o1 = (l15 == 0) ? (_Float16)1.f : (_Float16)0.f;
#pragma unroll
    for (int j = 0; j < 8; ++j) bones[j] = o1;
  }
  const int ds = wid * 16;
#pragma unroll
  for (int ks = 0; ks < 4; ++ks) {
    const int nb2 = (ks * 32 + quad * 8) ^ (l15 * 8);
    h8 a = *(const h8*)&smem[(ds + l15) * 128 + nb2];
#pragma unroll
    for (int et = 0; et < 4; ++et) {
      h8 bv = *(const h8*)&smem[(64 + et * 16 + l15) * 128 + nb2];
      cacc[et] = __builtin_amdgcn_mfma_f32_16x16x32_f16(a, bv, cacc[et], 0, 0, 0);
    }
    cacc[4] = __builtin_amdgcn_mfma_f32_16x16x32_f16(a, bones, cacc[4], 0, 0, 0);
  }
  const size_t pb = ((size_t)bh * 32 + lc) * 4160;
  const int dw = ds + quad * 4;
#pragma unroll
  for (int et = 0; et < 4; ++et)
#pragma unroll
    for (int r = 0; r < 4; ++r)
      part[pb + (size_t)(dw + r) * 64 + et * 16 + l15] = cacc[et][r];
  if (l15 == 0) {
#pragma unroll
    for (int r = 0; r < 4; ++r) part[pb + 4096 + dw + r] = cacc[4][r];
  }
}

// ---------------- kernel 3: reduce live partials + memkv, store ctx^T ----
__global__ __launch_bounds__(256) void reduce_ctx(const float* __restrict__ part,
                                                  const float* __restrict__ memkv,
                                                  const int* __restrict__ cnt,
                                                  _Float16* __restrict__ ctxt) {
  const int bh = blockIdx.x;
  const int dsl = blockIdx.y;
  const int h = bh & 15;
  const int tid = threadIdx.x;
  const int dl = tid >> 6, e = tid & 63;
  const int d = dsl * 4 + dl;
  const size_t pb = (size_t)bh * 32 * 4160;
  const int nch = (cnt[bh >> 4] + 127) >> 7;

  float den = 0.f;
  for (int c = 0; c < nch; ++c) den += part[pb + (size_t)c * 4160 + 4096 + d];
  float s = 0.f;
  for (int c = 0; c < nch; ++c) s += part[pb + (size_t)c * 4160 + (size_t)d * 64 + e];
#pragma unroll
  for (int j = 0; j < 4; ++j) {
    const float ek = __expf(memkv[(h * 4 + j) * 64 + d]);
    den += ek;
    s += ek * memkv[4096 + (h * 4 + j) * 64 + e];
  }
  ctxt[(size_t)bh * 4096 + (size_t)e * 64 + d] = (_Float16)(s / den);
}

// ---------------- kernel 4: q GEMM (n=64, 1 head/block) + exp/PV/out ----
// grid (16 heads, 128 m-blocks), compacted slots. Main loop SWAPS mfma
// operands -> acc transposed (l15 = x-slot, quad = q-col) -> P is
// d-vectorized -> h4 writes into [128 m][64 d] LDS, chunk^(m&7) swizzled
// (8 chunks/row, same scheme as As). PV: 4 waves x 32 rows, A = P-frags,
// B = e-major ctxt; out scattered via idx. 24KB LDS -> 5 blocks/CU.
__global__ __launch_bounds__(256, 5) void qpv(const _Float16* __restrict__ A,
                                              const _Float16* __restrict__ W,
                                              const _Float16* __restrict__ ctxt,
                                              const int* __restrict__ cnt,
                                              const int* __restrict__ idx,
                                              float* __restrict__ out) {
  const int my = blockIdx.y;
  const int b = my >> 5, lc = my & 31;
  const int cb = cnt[b];
  if (lc * 128 >= cb) return;

  __shared__ _Float16 smem[12288];  // As 16K + Bs 8K = 24KB; epi: P 16K
  _Float16* const As = smem;
  _Float16* const Bs = smem + 8192;
  const int tid = threadIdx.x;
  const int lane = tid & 63, wid = tid >> 6;
  const int wm = wid & 1, wn = wid >> 1;   // 2M x 2N (N halves of 32)
  const int l15 = lane & 15, quad = lane >> 4;
  const int h = blockIdx.x;            // head; q-rows 2048 + h*64 + (0..63)
  const int m0 = b * 4096 + lc * 128;  // compacted slot base

  const f4 z = {0.f, 0.f, 0.f, 0.f};
  f4 acc[4][2];
#pragma unroll
  for (int i = 0; i < 4; ++i)
#pragma unroll
    for (int j = 0; j < 2; ++j) acc[i][j] = z;

  const int swz = l15 & 7;
  const size_t qb = (size_t)(2048 + h * 64) * 1024;

  for (int kt = 0; kt < 16; ++kt) {
    const int k0 = kt * 64;
#pragma unroll
    for (int it = 0; it < 4; ++it) {
      const int idxl = it * 256 + tid;
      const int row = idxl >> 3, cg = idxl & 7;
      async16(A + ((size_t)(m0 + row) * 1024 + k0 + cg * 8), As + idxl * 8);
    }
#pragma unroll
    for (int it = 0; it < 2; ++it) {
      const int idxl = it * 256 + tid;
      const int row = idxl >> 3, cg = idxl & 7;
      async16(W + (qb + (size_t)row * 1024 + k0 + cg * 8), Bs + idxl * 8);
    }
    __syncthreads();
#pragma unroll
    for (int ks = 0; ks < 2; ++ks) {
      const int pc = ((ks << 2) | quad) ^ swz;
      h8 af[4], bf[2];
#pragma unroll
      for (int i = 0; i < 4; ++i)
        af[i] = *(const h8*)&As[(wm * 64 + i * 16 + l15) * 64 + pc * 8];
#pragma unroll
      for (int j = 0; j < 2; ++j)
        bf[j] = *(const h8*)&Bs[(wn * 32 + j * 16 + l15) * 64 + pc * 8];
#pragma unroll
      for (int i = 0; i < 4; ++i)
#pragma unroll
        for (int j = 0; j < 2; ++j)  // SWAPPED: acc transposed
          acc[i][j] = __builtin_amdgcn_mfma_f32_16x16x32_f16(bf[j], af[i], acc[i][j], 0, 0, 0);
    }
    __syncthreads();
  }

  // ---- P = exp(q/8) -> LDS [m][64d], chunk^(m&7) swizzled ----
#pragma unroll
  for (int i = 0; i < 4; ++i) {
    const int m = wm * 64 + i * 16 + l15;  // m&7 == l15&7
    _Float16* const prow = &smem[m * 64];
#pragma unroll
    for (int j = 0; j < 2; ++j) {
      h4 o;
#pragma unroll
      for (int r = 0; r < 4; ++r) o[r] = (_Float16)__expf(acc[i][j][r] * 0.125f);
      const int c3 = (wn * 4 + j * 2 + (quad >> 1)) ^ (l15 & 7);
      *(h4*)&prow[c3 * 8 + (quad & 1) * 4] = o;
    }
  }
  __syncthreads();

  // ---- PV: 4 waves x 32 rows each ----
  const int mb = wid * 32;
  const int bh = b * 16 + h;
  f4 cacc[2][5];
#pragma unroll
  for (int i = 0; i < 2; ++i)
#pragma unroll
    for (int j = 0; j < 5; ++j) cacc[i][j] = z;
  h8 bones;
  {
    const _Float16 o1 = (l15 == 0) ? (_Float16)1.f : (_Float16)0.f;
#pragma unroll
    for (int j = 0; j < 8; ++j) bones[j] = o1;
  }
#pragma unroll
  for (int ks = 0; ks < 2; ++ks) {
    h8 bf[4];
#pragma unroll
    for (int et = 0; et < 4; ++et)
      bf[et] = *(const h8*)&ctxt[(size_t)bh * 4096 +
                                 (size_t)(et * 16 + l15) * 64 + ks * 32 + quad * 8];
#pragma unroll
    for (int i2 = 0; i2 < 2; ++i2) {
      const int m = mb + i2 * 16 + l15;
      const int ch = ((ks * 4 + quad) ^ (l15 & 7)) * 8;
      h8 a = *(const h8*)&smem[m * 64 + ch];
#pragma unroll
      for (int et = 0; et < 4; ++et)
        cacc[i2][et] = __builtin_amdgcn_mfma_f32_16x16x32_f16(a, bf[et], cacc[i2][et], 0, 0, 0);
      cacc[i2][4] = __builtin_amdgcn_mfma_f32_16x16x32_f16(a, bones, cacc[i2][4], 0, 0, 0);
    }
  }
#pragma unroll
  for (int i2 = 0; i2 < 2; ++i2) {
#pragma unroll
    for (int r = 0; r < 4; ++r) {
      const int s = mb + i2 * 16 + quad * 4 + r;   // slot, uniform per quad
      const int j = lc * 128 + s;
      const float sb = __shfl(cacc[i2][4][r], lane & 48);
      if (j < cb) {
        const int row = b * 4096 + idx[b * 4096 + j];
        const float iv = 1.0f / sb;
#pragma unroll
        for (int et = 0; et < 4; ++et)
          out[(size_t)row * 1024 + h * 64 + et * 16 + l15] = cacc[i2][et][r] * iv;
      }
    }
  }
}

// ---------------- launch ----------------
extern "C" void kernel_launch(void* const* d_in, const int* in_sizes, int n_in,
                              void* d_out, int out_size, void* d_ws, size_t ws_size,
                              hipStream_t stream) {
  const float* x = (const float*)d_in[0];      // 16777216
  const float* w = (const float*)d_in[1];      // 3145728
  const float* memkv = (const float*)d_in[2];  // 8192
  const int* mask = (const int*)d_in[3];       // 16384
  float* out = (float*)d_out;

  char* ws = (char*)d_ws;
  _Float16* xh   = (_Float16*)(ws + 0);          //  33,554,432 (compacted+swizzled)
  _Float16* wh   = (_Float16*)(ws + 33554432);   //   6,291,456 (permuted+swizzled)
  float*    part = (float*)(ws + 39845888);      //  34,078,720 (32 chunks)
  _Float16* ctxt = (_Float16*)(ws + 73924608);   //     524,288
  int*      cnt  = (int*)(ws + 74448896);        //          16
  int*      idx  = (int*)(ws + 74448928);        //      65,536

  compact<<<dim3(4), dim3(1024), 0, stream>>>((const int4*)mask, cnt, idx);
  cvt_f16<<<dim3(26112), dim3(256), 0, stream>>>((const float4*)x, (const float4*)w,
                                                 mask, cnt, idx,
                                                 (h8*)xh, (h8*)wh, (float4*)out);
  kv_gemm<<<dim3(16, 128), dim3(256), 0, stream>>>(xh, wh, cnt, part);
  reduce_ctx<<<dim3(64, 16), dim3(256), 0, stream>>>(part, memkv, cnt, ctxt);
  qpv<<<dim3(16, 128), dim3(256), 0, stream>>>(xh, wh, ctxt, cnt, idx, out);
}

// Round 12
// 214.725 us; speedup vs baseline: 1.0754x; 1.0754x over previous
//
#include <hip/hip_runtime.h>

typedef _Float16 h8 __attribute__((ext_vector_type(8)));
typedef _Float16 h4 __attribute__((ext_vector_type(4)));
typedef float f4 __attribute__((ext_vector_type(4)));

typedef __attribute__((address_space(1))) const void GV;
typedef __attribute__((address_space(3))) void SV;

__device__ __forceinline__ void async16(const void* g, void* s) {
  __builtin_amdgcn_global_load_lds((GV*)g, (SV*)s, 16, 0, 0);
}

// x: (4,4096,1024) fp32; w_qkv: (3072,1024) fp32 rows e=h*192+d*3+t;
// mem_kv: (2,16,4,64) fp32; mask: (4,4096) int32; out: (4,4096,1024) fp32.
//
// COMPACTED PIPELINE: compact (scan) packs unmasked row ids to the front
// of idx[b]. cvt converts only live slots (swizzle keyed by slot), zero-
// fills tail to 128 boundary, plus W permute+swizzle and masked-out-row
// zeroing. GEMMs read xh linearly; blocks past cnt[b] exit.
// kv_gemm (256,4): 128-reg cap = exact 64 VGPR + 64 AGPR fit, 4 blk/CU.
// XCD SWIZZLE (T1): flat block id f -> xcd = f&7 owns a stride-8
// interleaved set of m-chunks (mc = (f>>3 / nN)*8 + xcd), so each A-tile
// is fetched by exactly ONE XCD's L2 (was: 16 n-blocks of one m-chunk
// round-robined over all 8 XCDs -> 3.5x A over-fetch, FETCH 75MB vs 21
// ideal). Stride-8 interleave keeps per-batch dead-chunk tails balanced
// across XCDs. Bijective (nwg%8==0).
// xh/wh BANK-SWIZZLED: chunk ch ^= (slot&7) within each 128-B window.
// wh rows PERMUTED: [0,2048) = [h][k:64|v:64], [2048,3072) = [h][q:64].

#define XC 2097152   // xh h8-chunk positions (16777216/8)
#define WC 393216    // w h8-chunks (3145728/8)
#define ZC 4194304   // out float4 count (zero pass)

// ---------------- kernel 0: per-batch mask compaction (scan) -------------
__global__ __launch_bounds__(1024) void compact(const int4* __restrict__ mask4,
                                                int* __restrict__ cnt,
                                                int* __restrict__ idx) {
  const int b = blockIdx.x;
  const int t = threadIdx.x;            // 0..1023
  const int lane = t & 63, w = t >> 6;  // 16 waves

  const int4 m4 = mask4[b * 1024 + t];
  int m[4] = {m4.x, m4.y, m4.z, m4.w};
  const int c = (m[0] != 0) + (m[1] != 0) + (m[2] != 0) + (m[3] != 0);

  int inc = c;
#pragma unroll
  for (int off = 1; off < 64; off <<= 1) {
    const int v = __shfl_up(inc, off);
    if (lane >= off) inc += v;
  }
  __shared__ int wtot[16];
  if (lane == 63) wtot[w] = inc;
  __syncthreads();
  int prev = 0;
#pragma unroll
  for (int i = 0; i < 16; ++i)
    if (i < w) prev += wtot[i];
  const int excl = prev + inc - c;

  if (t == 1023) cnt[b] = excl + c;

  int* const ib = idx + b * 4096;
  int p = excl;
  int q = t * 4 - excl;
#pragma unroll
  for (int r = 0; r < 4; ++r) {
    const int row = t * 4 + r;
    if (m[r]) ib[p++] = row;
    else      ib[4095 - q++] = row;
  }
}

// ---------------- kernel 1: cvt (live slots only) + W + out-zero ---------
__global__ __launch_bounds__(256) void cvt_f16(const float4* __restrict__ x,
                                               const float4* __restrict__ w,
                                               const int* __restrict__ mask,
                                               const int* __restrict__ cnt,
                                               const int* __restrict__ idx,
                                               h8* __restrict__ xh,
                                               h8* __restrict__ wh,
                                               float4* __restrict__ out) {
  int t = blockIdx.x * 256 + threadIdx.x;
  if (t < XC) {
    const int slot = t >> 7, cd = t & 127;   // dest chunk
    const int b = slot >> 12, s = slot & 4095;
    const int cb = cnt[b];
    const int lim = (cb + 127) & ~127;
    if (s < lim) {
      h8 o;
      if (s < cb) {
        const int ri = idx[b * 4096 + s];
        const int cs = (cd & 120) | ((cd & 7) ^ (s & 7));  // src chunk
        const size_t rb = (size_t)(b * 4096 + ri) * 256;
        float4 a = x[rb + cs * 2], bb = x[rb + cs * 2 + 1];
        o = h8{(_Float16)a.x,  (_Float16)a.y,  (_Float16)a.z,  (_Float16)a.w,
               (_Float16)bb.x, (_Float16)bb.y, (_Float16)bb.z, (_Float16)bb.w};
      } else {
        o = h8{(_Float16)0.f, (_Float16)0.f, (_Float16)0.f, (_Float16)0.f,
               (_Float16)0.f, (_Float16)0.f, (_Float16)0.f, (_Float16)0.f};
      }
      xh[(size_t)slot * 128 + cd] = o;
    }
  } else if (t < XC + WC) {
    const int u = t - XC;  // 0..393215
    const int rp = u >> 7, c7 = u & 127;
    int sr;
    if (rp < 2048) {
      int h = rp >> 7, c = rp & 127;
      sr = h * 192 + ((c < 64) ? (c * 3 + 1) : ((c - 64) * 3 + 2));
    } else {
      int q = rp - 2048;
      sr = (q >> 6) * 192 + (q & 63) * 3;
    }
    const int dst = (rp << 7) | (c7 & 120) | ((c7 & 7) ^ (rp & 7));
    float4 a = w[sr * 256 + c7 * 2], b = w[sr * 256 + c7 * 2 + 1];
    h8 o = {(_Float16)a.x, (_Float16)a.y, (_Float16)a.z, (_Float16)a.w,
            (_Float16)b.x, (_Float16)b.y, (_Float16)b.z, (_Float16)b.w};
    wh[dst] = o;
  } else {
    const int u = t - (XC + WC);   // 0..ZC-1
    const int row = u >> 8, c = u & 255;
    if (!mask[row]) {
      const float4 z4 = {0.f, 0.f, 0.f, 0.f};
      out[(size_t)row * 256 + c] = z4;
    }
  }
}

// ---------------- kernel 2: kv GEMM + ctx-partial epilogue (128^2) -------
// grid (16 n-tiles, 128 m-tiles), 256 thr = 4 waves (2x2), BK=64.
// (256,4): 128-reg cap = exact 64 VGPR + 64 AGPR fit, 4 blocks/CU.
// XCD swizzle: f = bx + 16*by; mc = (f>>7)*8 + (f&7); n = (f>>3)&15.
__global__ __launch_bounds__(256, 4) void kv_gemm(const _Float16* __restrict__ A,
                                                  const _Float16* __restrict__ W,
                                                  const int* __restrict__ cnt,
                                                  float* __restrict__ part) {
  const int f = blockIdx.x + (blockIdx.y << 4);
  const int mc = ((f >> 7) << 3) + (f & 7);   // msub*8 + xcd, 0..127
  const int b = mc >> 5, lc = mc & 31;
  const int cb = cnt[b];
  if (lc * 128 >= cb) return;

  __shared__ _Float16 smem[128 * 128];  // 32 KB: As 16K + Bs 16K; epi reuse
  _Float16* const As = smem;
  _Float16* const Bs = smem + 8192;
  const int tid = threadIdx.x;
  const int lane = tid & 63, wid = tid >> 6;
  const int wm = wid & 1, wn = wid >> 1;
  const int l15 = lane & 15, quad = lane >> 4;
  const int n0 = ((f >> 3) & 15) << 7;
  const int m0 = b * 4096 + lc * 128;  // compacted slot base

  const f4 z = {0.f, 0.f, 0.f, 0.f};
  f4 acc[4][4];
#pragma unroll
  for (int i = 0; i < 4; ++i)
#pragma unroll
    for (int j = 0; j < 4; ++j) acc[i][j] = z;

  const int swz = l15 & 7;

  for (int kt = 0; kt < 16; ++kt) {
    const int k0 = kt * 64;
#pragma unroll
    for (int it = 0; it < 4; ++it) {
      const int idxl = it * 256 + tid;
      const int row = idxl >> 3, cg = idxl & 7;
      async16(A + ((size_t)(m0 + row) * 1024 + k0 + cg * 8), As + idxl * 8);
      async16(W + ((size_t)(n0 + row) * 1024 + k0 + cg * 8), Bs + idxl * 8);
    }
    __syncthreads();
#pragma unroll
    for (int ks = 0; ks < 2; ++ks) {
      const int pc = ((ks << 2) | quad) ^ swz;
      h8 af[4], bf[4];
#pragma unroll
      for (int i = 0; i < 4; ++i)
        af[i] = *(const h8*)&As[(wm * 64 + i * 16 + l15) * 64 + pc * 8];
#pragma unroll
      for (int j = 0; j < 4; ++j)
        bf[j] = *(const h8*)&Bs[(wn * 64 + j * 16 + l15) * 64 + pc * 8];
#pragma unroll
      for (int i = 0; i < 4; ++i)
#pragma unroll
        for (int j = 0; j < 4; ++j)
          acc[i][j] = __builtin_amdgcn_mfma_f32_16x16x32_f16(af[i], bf[j], acc[i][j], 0, 0, 0);
    }
    __syncthreads();
  }

  // ---- kv epilogue: exp(k) for valid slots, LDS round-trip, ctx partial --
  const int h = n0 >> 7;
  const int bh = b * 16 + h;
  const int jbase = lc * 128;
#pragma unroll
  for (int i = 0; i < 4; ++i) {
    const int nb = wm * 64 + i * 16 + quad * 4;
#pragma unroll
    for (int j = 0; j < 4; ++j) {
      const int c = wn * 64 + j * 16 + l15;
      h4 o;
      if (wn == 0) {
#pragma unroll
        for (int r = 0; r < 4; ++r)
          o[r] = (_Float16)((jbase + nb + r < cb) ? __expf(acc[i][j][r]) : 0.f);
      } else {
#pragma unroll
        for (int r = 0; r < 4; ++r) o[r] = (_Float16)acc[i][j][r];
      }
      *(h4*)&smem[c * 128 + (nb ^ (l15 * 8))] = o;
    }
  }
  __syncthreads();
  f4 cacc[5];
#pragma unroll
  for (int i = 0; i < 5; ++i) cacc[i] = z;
  h8 bones;
  {
    const _Float16 o1 = (l15 == 0) ? (_Float16)1.f : (_Float16)0.f;
#pragma unroll
    for (int j = 0; j < 8; ++j) bones[j] = o1;
  }
  const int ds = wid * 16;
#pragma unroll
  for (int ks = 0; ks < 4; ++ks) {
    const int nb2 = (ks * 32 + quad * 8) ^ (l15 * 8);
    h8 a = *(const h8*)&smem[(ds + l15) * 128 + nb2];
#pragma unroll
    for (int et = 0; et < 4; ++et) {
      h8 bv = *(const h8*)&smem[(64 + et * 16 + l15) * 128 + nb2];
      cacc[et] = __builtin_amdgcn_mfma_f32_16x16x32_f16(a, bv, cacc[et], 0, 0, 0);
    }
    cacc[4] = __builtin_amdgcn_mfma_f32_16x16x32_f16(a, bones, cacc[4], 0, 0, 0);
  }
  const size_t pb = ((size_t)bh * 32 + lc) * 4160;
  const int dw = ds + quad * 4;
#pragma unroll
  for (int et = 0; et < 4; ++et)
#pragma unroll
    for (int r = 0; r < 4; ++r)
      part[pb + (size_t)(dw + r) * 64 + et * 16 + l15] = cacc[et][r];
  if (l15 == 0) {
#pragma unroll
    for (int r = 0; r < 4; ++r) part[pb + 4096 + dw + r] = cacc[4][r];
  }
}

// ---------------- kernel 3: reduce live partials + memkv, store ctx^T ----
__global__ __launch_bounds__(256) void reduce_ctx(const float* __restrict__ part,
                                                  const float* __restrict__ memkv,
                                                  const int* __restrict__ cnt,
                                                  _Float16* __restrict__ ctxt) {
  const int bh = blockIdx.x;
  const int dsl = blockIdx.y;
  const int h = bh & 15;
  const int tid = threadIdx.x;
  const int dl = tid >> 6, e = tid & 63;
  const int d = dsl * 4 + dl;
  const size_t pb = (size_t)bh * 32 * 4160;
  const int nch = (cnt[bh >> 4] + 127) >> 7;

  float den = 0.f;
  for (int c = 0; c < nch; ++c) den += part[pb + (size_t)c * 4160 + 4096 + d];
  float s = 0.f;
  for (int c = 0; c < nch; ++c) s += part[pb + (size_t)c * 4160 + (size_t)d * 64 + e];
#pragma unroll
  for (int j = 0; j < 4; ++j) {
    const float ek = __expf(memkv[(h * 4 + j) * 64 + d]);
    den += ek;
    s += ek * memkv[4096 + (h * 4 + j) * 64 + e];
  }
  ctxt[(size_t)bh * 4096 + (size_t)e * 64 + d] = (_Float16)(s / den);
}

// ---------------- kernel 4: q GEMM + fused exp/PV/out epilogue -----------
// grid (8 n-tiles, 128 m-tiles), compacted slots (linear reads). Main loop
// SWAPS mfma operands -> acc transposed (l15 = x-slot, quad = q-col) -> P
// d-vectorized -> h4 writes into row-major swizzled LDS P[m][dcol]. PV
// consumes P as A-frags + e-major ctxt as B-frags; out rows scattered via
// idx. XCD swizzle: f = bx + 8*by; mc = (f>>6)*8 + (f&7); n = (f>>3)&7.
__global__ __launch_bounds__(256, 3) void qpv(const _Float16* __restrict__ A,
                                              const _Float16* __restrict__ W,
                                              const _Float16* __restrict__ ctxt,
                                              const int* __restrict__ cnt,
                                              const int* __restrict__ idx,
                                              float* __restrict__ out) {
  const int f = blockIdx.x + (blockIdx.y << 3);
  const int mc = ((f >> 6) << 3) + (f & 7);   // msub*8 + xcd, 0..127
  const int b = mc >> 5, lc = mc & 31;
  const int cb = cnt[b];
  if (lc * 128 >= cb) return;

  __shared__ _Float16 smem[128 * 128];  // As 16K + Bs 16K; epi: P 32K
  _Float16* const As = smem;
  _Float16* const Bs = smem + 8192;
  const int tid = threadIdx.x;
  const int lane = tid & 63, wid = tid >> 6;
  const int wm = wid & 1, wn = wid >> 1;
  const int l15 = lane & 15, quad = lane >> 4;
  const int n0 = ((f >> 3) & 7) << 7;  // q-col window within [0,1024)
  const int m0 = b * 4096 + lc * 128;  // compacted slot base

  const f4 z = {0.f, 0.f, 0.f, 0.f};
  f4 acc[4][4];
#pragma unroll
  for (int i = 0; i < 4; ++i)
#pragma unroll
    for (int j = 0; j < 4; ++j) acc[i][j] = z;

  const int swz = l15 & 7;

  for (int kt = 0; kt < 16; ++kt) {
    const int k0 = kt * 64;
#pragma unroll
    for (int it = 0; it < 4; ++it) {
      const int idxl = it * 256 + tid;
      const int row = idxl >> 3, cg = idxl & 7;
      async16(A + ((size_t)(m0 + row) * 1024 + k0 + cg * 8), As + idxl * 8);
      async16(W + ((size_t)(2048 + n0 + row) * 1024 + k0 + cg * 8), Bs + idxl * 8);
    }
    __syncthreads();
#pragma unroll
    for (int ks = 0; ks < 2; ++ks) {
      const int pc = ((ks << 2) | quad) ^ swz;
      h8 af[4], bf[4];
#pragma unroll
      for (int i = 0; i < 4; ++i)
        af[i] = *(const h8*)&As[(wm * 64 + i * 16 + l15) * 64 + pc * 8];
#pragma unroll
      for (int j = 0; j < 4; ++j)
        bf[j] = *(const h8*)&Bs[(wn * 64 + j * 16 + l15) * 64 + pc * 8];
#pragma unroll
      for (int i = 0; i < 4; ++i)
#pragma unroll
        for (int j = 0; j < 4; ++j)  // SWAPPED: acc transposed
          acc[i][j] = __builtin_amdgcn_mfma_f32_16x16x32_f16(bf[j], af[i], acc[i][j], 0, 0, 0);
    }
    __syncthreads();
  }

  // ---- P = exp(q/8) -> LDS [m][dcol], chunk-swizzled ----
#pragma unroll
  for (int i = 0; i < 4; ++i) {
    const int m = wm * 64 + i * 16 + l15;  // m&7 == l15&7
    _Float16* const prow = &smem[m * 128 + wn * 64];
#pragma unroll
    for (int j = 0; j < 4; ++j) {
      h4 o;
#pragma unroll
      for (int r = 0; r < 4; ++r) o[r] = (_Float16)__expf(acc[i][j][r] * 0.125f);
      const int c3 = (j * 2 + (quad >> 1)) ^ (l15 & 7);
      *(h4*)&prow[c3 * 8 + (quad & 1) * 4] = o;
    }
  }
  __syncthreads();

  // ---- PV: wave = (row-half wid&1, head wid>>1) ----
  const int hw = wid >> 1;
  const int mb = (wid & 1) * 64;
  const int h = (n0 >> 6) + hw;
  const int bh = b * 16 + h;
  f4 cacc[4][5];
#pragma unroll
  for (int i = 0; i < 4; ++i)
#pragma unroll
    for (int j = 0; j < 5; ++j) cacc[i][j] = z;
  h8 bones;
  {
    const _Float16 o1 = (l15 == 0) ? (_Float16)1.f : (_Float16)0.f;
#pragma unroll
    for (int j = 0; j < 8; ++j) bones[j] = o1;
  }
#pragma unroll
  for (int ks = 0; ks < 2; ++ks) {
    h8 bf[4];
#pragma unroll
    for (int et = 0; et < 4; ++et)
      bf[et] = *(const h8*)&ctxt[(size_t)bh * 4096 +
                                 (size_t)(et * 16 + l15) * 64 + ks * 32 + quad * 8];
#pragma unroll
    for (int i2 = 0; i2 < 4; ++i2) {
      const int m = mb + i2 * 16 + l15;
      const int ch = ((ks * 4 + quad) ^ (l15 & 7)) * 8;
      h8 a = *(const h8*)&smem[m * 128 + hw * 64 + ch];
#pragma unroll
      for (int et = 0; et < 4; ++et)
        cacc[i2][et] = __builtin_amdgcn_mfma_f32_16x16x32_f16(a, bf[et], cacc[i2][et], 0, 0, 0);
      cacc[i2][4] = __builtin_amdgcn_mfma_f32_16x16x32_f16(a, bones, cacc[i2][4], 0, 0, 0);
    }
  }
#pragma unroll
  for (int i2 = 0; i2 < 4; ++i2) {
#pragma unroll
    for (int r = 0; r < 4; ++r) {
      const int s = mb + i2 * 16 + quad * 4 + r;   // slot, uniform per quad
      const int j = lc * 128 + s;
      const float sb = __shfl(cacc[i2][4][r], lane & 48);
      if (j < cb) {
        const int row = b * 4096 + idx[b * 4096 + j];
        const float iv = 1.0f / sb;
#pragma unroll
        for (int et = 0; et < 4; ++et)
          out[(size_t)row * 1024 + h * 64 + et * 16 + l15] = cacc[i2][et][r] * iv;
      }
    }
  }
}

// ---------------- launch ----------------
extern "C" void kernel_launch(void* const* d_in, const int* in_sizes, int n_in,
                              void* d_out, int out_size, void* d_ws, size_t ws_size,
                              hipStream_t stream) {
  const float* x = (const float*)d_in[0];      // 16777216
  const float* w = (const float*)d_in[1];      // 3145728
  const float* memkv = (const float*)d_in[2];  // 8192
  const int* mask = (const int*)d_in[3];       // 16384
  float* out = (float*)d_out;

  char* ws = (char*)d_ws;
  _Float16* xh   = (_Float16*)(ws + 0);          //  33,554,432 (compacted+swizzled)
  _Float16* wh   = (_Float16*)(ws + 33554432);   //   6,291,456 (permuted+swizzled)
  float*    part = (float*)(ws + 39845888);      //  34,078,720 (32 chunks)
  _Float16* ctxt = (_Float16*)(ws + 73924608);   //     524,288
  int*      cnt  = (int*)(ws + 74448896);        //          16
  int*      idx  = (int*)(ws + 74448928);        //      65,536

  compact<<<dim3(4), dim3(1024), 0, stream>>>((const int4*)mask, cnt, idx);
  cvt_f16<<<dim3(26112), dim3(256), 0, stream>>>((const float4*)x, (const float4*)w,
                                                 mask, cnt, idx,
                                                 (h8*)xh, (h8*)wh, (float4*)out);
  kv_gemm<<<dim3(16, 128), dim3(256), 0, stream>>>(xh, wh, cnt, part);
  reduce_ctx<<<dim3(64, 16), dim3(256), 0, stream>>>(part, memkv, cnt, ctxt);
  qpv<<<dim3(8, 128), dim3(256), 0, stream>>>(xh, wh, ctxt, cnt, idx, out);
}